// Round 1
// baseline (106.451 us; speedup 1.0000x reference)
//
#include <hip/hip_runtime.h>
#include <math.h>

#define NB 8
#define KC 64
#define S1C 5
#define CC 128
#define PP 1936
#define PT 32
#define NPT 61             /* ceil(1936/32) */
#define NTILE (NB * NPT)   /* 488 */
#define ALPHAF 1500.0f
#define EPSF 1e-12f

/* ws layout (floats):
   [0, 65536)      cenPk: pre-split bf16 hi/lo cen B-fragments
                   [ks(4)][nt(32)][lane(64)][hi short8, lo short8]
   [65536, 66048)  gbias[512]  (m' = 8k+s padded; s>=5 -> -3e38)
   [66048, ...)    part[NTILE][KC][CC] ; ps[NTILE][KC]            */
#define WS_CENPK 65536
#define WS_GBIAS 512
#define WS_HDR   (WS_CENPK + WS_GBIAS)
#define WS_PART  ((size_t)NTILE * KC * CC)
#define WS_MAIN_FLOATS (WS_HDR + WS_PART + (size_t)NTILE * KC)

typedef __attribute__((ext_vector_type(8))) short short8;
typedef __attribute__((ext_vector_type(4))) float f32x4;

/* pack fp32 -> (bf16_hi << 16) | bf16_lo  (hi = truncate, lo = residual) */
__device__ __forceinline__ unsigned pack_bf16s(float x) {
    unsigned u  = __float_as_uint(x);
    unsigned hi = u & 0xffff0000u;
    float lo    = x - __uint_as_float(hi);
    return hi | (__float_as_uint(lo) >> 16);
}

__device__ __forceinline__ void unpack8(const int4 q0, const int4 q1,
                                        short8& h, short8& l) {
    const int d[8] = {q0.x, q0.y, q0.z, q0.w, q1.x, q1.y, q1.z, q1.w};
#pragma unroll
    for (int j = 0; j < 8; ++j) {
        h[j] = (short)((unsigned)d[j] >> 16);
        l[j] = (short)((unsigned)d[j] & 0xffffu);
    }
}

__device__ __forceinline__ void split8(const float4 a, const float4 b,
                                       short8& h, short8& l) {
    const float f[8] = {a.x, a.y, a.z, a.w, b.x, b.y, b.z, b.w};
#pragma unroll
    for (int j = 0; j < 8; ++j) {
        const unsigned u  = __float_as_uint(f[j]);
        const unsigned hi = u & 0xffff0000u;
        const float lo    = f[j] - __uint_as_float(hi);
        h[j] = (short)(hi >> 16);
        l[j] = (short)(__float_as_uint(lo) >> 16);
    }
}

// ---------------------------------------------------------------------------
// k0: precompute bias[512] and pre-split bf16 hi/lo cen fragments in MFMA
// B-operand lane layout. 32 blocks (one per m'-tile nt) x 64 threads.
// Ran every iteration (ws is re-poisoned by the harness).
// ---------------------------------------------------------------------------
__global__ __launch_bounds__(64) void k0_pack(
    const float* __restrict__ cen, unsigned* __restrict__ cenPk,
    float* __restrict__ gbias)
{
    const int nt   = blockIdx.x;      // 0..31
    const int l    = threadIdx.x;     // 0..63
    const int l15  = l & 15;
    const int quad = l >> 4;
    const int mp   = nt * 16 + l15;   // padded m' = 8k+s
    const int s    = mp & 7;
    const bool valid = (s < 5);
    const int wrow = 5 * (mp >> 3) + s;
    short8* dst8 = (short8*)cenPk;
    float ss = 0.f;
#pragma unroll
    for (int ks = 0; ks < 4; ++ks) {
        float4 v0 = make_float4(0.f, 0.f, 0.f, 0.f), v1 = v0;
        if (valid) {
            const float* wp = cen + (size_t)wrow * CC + ks * 32 + quad * 8;
            v0 = *(const float4*)wp;
            v1 = *(const float4*)(wp + 4);
        }
        ss += v0.x * v0.x + v0.y * v0.y + v0.z * v0.z + v0.w * v0.w
            + v1.x * v1.x + v1.y * v1.y + v1.z * v1.z + v1.w * v1.w;
        short8 h, lo;
        split8(v0, v1, h, lo);
        const int base = ((ks * 32 + nt) * 64 + l) * 2;
        dst8[base]     = h;
        dst8[base + 1] = lo;
    }
    ss += __shfl_xor(ss, 16);
    ss += __shfl_xor(ss, 32);
    if (quad == 0) gbias[mp] = valid ? (-ALPHAF * sqrtf(ss)) : -3.0e38f;
}

// ---------------------------------------------------------------------------
// k1: per (n, p-tile of 32), 512 threads = 8 waves, 3 barriers.
// 50.8 KB LDS + <=128 VGPR (launch_bounds(512,4)) -> 2 blocks/CU: two
// independent barrier domains overlap each other's stalls.
// phase1: logits D[p][m'] MFMA, B-frags direct from cenPk (no split VALU).
// phase2: alpha (wave partials + finalize), beta (8-lane shfl), wa pack.
// phase3: C[k][c] = sum_p wa*x via bf16-split MFMA (K=32 = whole tile).
// ---------------------------------------------------------------------------
__global__ __launch_bounds__(512, 4) void k1_main(
    const float* __restrict__ x, const unsigned* __restrict__ cenPk,
    const float* __restrict__ gbias,
    float* __restrict__ sa_out, float* __restrict__ outC,
    float* __restrict__ outS, int mode)
{
    __shared__ unsigned xbuf[PT * 132];   // 16896 B  [p][c] packed x^T
    __shared__ unsigned xc[CC * 36];      // 18432 B  [c][p] packed x
    __shared__ unsigned war[KC * 36];     //  9216 B  packed wa [k][p]
    __shared__ float2   ap[8 * 66];       //  4224 B  alpha partials [wid][p]
    __shared__ float    bias_p[512];      //  2048 B

    const int tid  = threadIdx.x;
    const int lane = tid & 63;
    const int wid  = tid >> 6;            // 0..7
    const int quad = lane >> 4;
    const int l15  = lane & 15;
    const int bx   = blockIdx.x;
    const int n    = bx / NPT;
    const int pt   = bx - n * NPT;
    const int p0   = pt * PT;

    // ---- phase 0: stage x once into BOTH layouts; bias from gbias ----
    const float* xn = x + (size_t)n * CC * PP;
    {
        const int c  = tid >> 2;          // 0..127
        const int po = (tid & 3) * 8;     // 0,8,16,24
        float4 v0 = make_float4(0.f, 0.f, 0.f, 0.f), v1 = v0;
        if (p0 + po < PP) {               // PP % 8 == 0: full or empty
            const float* src = xn + (size_t)c * PP + p0 + po;
            v0 = *(const float4*)src;
            v1 = *(const float4*)(src + 4);
        }
        unsigned pk[8];
        pk[0] = pack_bf16s(v0.x); pk[1] = pack_bf16s(v0.y);
        pk[2] = pack_bf16s(v0.z); pk[3] = pack_bf16s(v0.w);
        pk[4] = pack_bf16s(v1.x); pk[5] = pack_bf16s(v1.y);
        pk[6] = pack_bf16s(v1.z); pk[7] = pack_bf16s(v1.w);
        *(int4*)(&xc[c * 36 + po])     = *(const int4*)&pk[0];
        *(int4*)(&xc[c * 36 + po + 4]) = *(const int4*)&pk[4];
#pragma unroll
        for (int j = 0; j < 8; ++j) xbuf[(po + j) * 132 + c] = pk[j];
    }
    bias_p[tid] = gbias[tid];
    __syncthreads();

    // ---- phase 1: logits MFMA; wave handles nt = 4wid..4wid+3 ----
    f32x4 dacc[2][4];
#pragma unroll
    for (int a = 0; a < 2; ++a)
#pragma unroll
        for (int i = 0; i < 4; ++i)
            dacc[a][i] = (f32x4){0.f, 0.f, 0.f, 0.f};

    const short8* cpk8 = (const short8*)cenPk;
#pragma unroll 1
    for (int ks = 0; ks < 4; ++ks) {
        short8 ah[2], al[2];
#pragma unroll
        for (int a = 0; a < 2; ++a) {
            const int abase = (a * 16 + l15) * 132 + ks * 32 + quad * 8;
            const int4 q0 = *(const int4*)(&xbuf[abase]);
            const int4 q1 = *(const int4*)(&xbuf[abase + 4]);
            unpack8(q0, q1, ah[a], al[a]);
        }
#pragma unroll
        for (int i = 0; i < 4; ++i) {
            const int boff = ((ks * 32 + 4 * wid + i) * 64 + lane) * 2;
            const short8 bh = cpk8[boff];
            const short8 bl = cpk8[boff + 1];
#pragma unroll
            for (int a = 0; a < 2; ++a) {
                dacc[a][i] = __builtin_amdgcn_mfma_f32_16x16x32_bf16(ah[a], bh, dacc[a][i], 0, 0, 0);
                dacc[a][i] = __builtin_amdgcn_mfma_f32_16x16x32_bf16(ah[a], bl, dacc[a][i], 0, 0, 0);
                dacc[a][i] = __builtin_amdgcn_mfma_f32_16x16x32_bf16(al[a], bh, dacc[a][i], 0, 0, 0);
            }
        }
    }

    // lg = 2*ALPHA*dot + bias (invalid s>=5 columns -> -3e38)
#pragma unroll
    for (int i = 0; i < 4; ++i) {
        const float bv = bias_p[(4 * wid + i) * 16 + l15];
#pragma unroll
        for (int a = 0; a < 2; ++a)
#pragma unroll
            for (int r = 0; r < 4; ++r)
                dacc[a][i][r] = 2.f * ALPHAF * dacc[a][i][r] + bv;
    }

    // alpha partials over this wave's 8 k (i-regs x shfl_xor 8); s0 lanes hold lg0
#pragma unroll
    for (int a = 0; a < 2; ++a) {
        f32x4 mx4, se4;
#pragma unroll
        for (int r = 0; r < 4; ++r) {
            float m_ = fmaxf(fmaxf(dacc[a][0][r], dacc[a][1][r]),
                             fmaxf(dacc[a][2][r], dacc[a][3][r]));
            m_ = fmaxf(m_, __shfl_xor(m_, 8));
            float se = __expf(dacc[a][0][r] - m_) + __expf(dacc[a][1][r] - m_)
                     + __expf(dacc[a][2][r] - m_) + __expf(dacc[a][3][r] - m_);
            se += __shfl_xor(se, 8);
            mx4[r] = m_; se4[r] = se;
        }
        if (l15 == 0) {
#pragma unroll
            for (int r = 0; r < 4; ++r)
                ap[wid * 66 + a * 16 + 4 * quad + r] = make_float2(mx4[r], se4[r]);
        }
    }
    __syncthreads();

    // ---- phase 2: alpha finalize (lane = p), beta + sa, war, psum ----
    float gmv, arv;
    {
        float gm = -3.0e38f;
#pragma unroll
        for (int w = 0; w < 8; ++w) gm = fmaxf(gm, ap[w * 66 + lane].x);
        float ssum = 0.f;
#pragma unroll
        for (int w = 0; w < 8; ++w) {
            const float2 v = ap[w * 66 + lane];
            ssum += v.y * __expf(v.x - gm);
        }
        gmv = gm; arv = 1.0f / ssum;
    }

    float* san = sa_out + (size_t)n * KC * PP;
    float psum[4] = {0.f, 0.f, 0.f, 0.f};
    const bool is_s0 = ((l15 & 7) == 0);
#pragma unroll
    for (int a = 0; a < 2; ++a) {
#pragma unroll
        for (int i = 0; i < 4; ++i) {
            const f32x4 lg = dacc[a][i];
            f32x4 sav; unsigned wpk[4];
#pragma unroll
            for (int r = 0; r < 4; ++r) {
                float m_ = lg[r];
                m_ = fmaxf(m_, __shfl_xor(m_, 1));
                m_ = fmaxf(m_, __shfl_xor(m_, 2));
                m_ = fmaxf(m_, __shfl_xor(m_, 4));
                const float e_ = __expf(lg[r] - m_);
                float d_ = e_;
                d_ += __shfl_xor(d_, 1);
                d_ += __shfl_xor(d_, 2);
                d_ += __shfl_xor(d_, 4);
                const int p = a * 16 + 4 * quad + r;
                const float gm_p = __shfl(gmv, p);
                const float ar_p = __shfl(arv, p);
                const float sa = __expf(lg[r] - gm_p) * ar_p * (e_ / d_);
                const bool pvalid = (p0 + p) < PP;
                const float wa = pvalid ? (1.0f + sa) : 0.0f;
                sav[r] = sa;
                wpk[r] = pack_bf16s(wa);
                psum[i] += wa;
            }
            const int k = 8 * wid + 2 * i + (l15 >> 3);
            if (is_s0) {
                *(int4*)(&war[k * 36 + a * 16 + 4 * quad]) = *(const int4*)wpk;
                const int pg = p0 + a * 16 + 4 * quad;
                if (pg < PP) *(float4*)(&san[(size_t)k * PP + pg]) = *(const float4*)&sav;
            }
        }
    }
#pragma unroll
    for (int i = 0; i < 4; ++i) {
        float s = psum[i];
        s += __shfl_xor(s, 16);
        s += __shfl_xor(s, 32);
        if (is_s0 && quad == 0) {
            const int k = 8 * wid + 2 * i + (l15 >> 3);
            if (mode == 0) outS[(size_t)bx * KC + k] = s;
            else           atomicAdd(&outS[(size_t)n * KC + k], s);
        }
    }
    __syncthreads();

    // ---- phase 3: C[k][c] MFMA; wave tile: kt = wid&3, ct0 = (wid>>2)*4 ----
    const int kt  = wid & 3;
    const int ct0 = (wid >> 2) * 4;
    short8 ah2, al2;
    {
        const int abase = (kt * 16 + l15) * 36 + quad * 8;
        const int4 qa0 = *(const int4*)(&war[abase]);
        const int4 qa1 = *(const int4*)(&war[abase + 4]);
        unpack8(qa0, qa1, ah2, al2);
    }
    f32x4 cacc[4];
#pragma unroll
    for (int t = 0; t < 4; ++t) cacc[t] = (f32x4){0.f, 0.f, 0.f, 0.f};
#pragma unroll
    for (int t = 0; t < 4; ++t) {
        const int c = (ct0 + t) * 16 + l15;
        const int bbase = c * 36 + quad * 8;
        const int4 qb0 = *(const int4*)(&xc[bbase]);
        const int4 qb1 = *(const int4*)(&xc[bbase + 4]);
        short8 bh, bl;
        unpack8(qb0, qb1, bh, bl);
        cacc[t] = __builtin_amdgcn_mfma_f32_16x16x32_bf16(ah2, bh, cacc[t], 0, 0, 0);
        cacc[t] = __builtin_amdgcn_mfma_f32_16x16x32_bf16(ah2, bl, cacc[t], 0, 0, 0);
        cacc[t] = __builtin_amdgcn_mfma_f32_16x16x32_bf16(al2, bh, cacc[t], 0, 0, 0);
    }
    if (mode == 0) {
        float* dst = outC + (size_t)bx * KC * CC;
#pragma unroll
        for (int t = 0; t < 4; ++t) {
            const int c = (ct0 + t) * 16 + l15;
#pragma unroll
            for (int r = 0; r < 4; ++r)
                dst[(kt * 16 + 4 * quad + r) * CC + c] = cacc[t][r];
        }
    } else {
        float* dst = outC + (size_t)n * KC * CC;
#pragma unroll
        for (int t = 0; t < 4; ++t) {
            const int c = (ct0 + t) * 16 + l15;
#pragma unroll
            for (int r = 0; r < 4; ++r)
                atomicAdd(&dst[(kt * 16 + 4 * quad + r) * CC + c], cacc[t][r]);
        }
    }
}

// ---------------------------------------------------------------------------
// k2 (slab mode): reduce 61 partial slabs, subtract rep*Swa, normalize, /8
// ---------------------------------------------------------------------------
__global__ __launch_bounds__(128) void k2_slab(
    const float* __restrict__ part, const float* __restrict__ ps,
    const float* __restrict__ cen, float* __restrict__ flat)
{
    __shared__ float w2[2];
    const int b = blockIdx.x;        // n*64 + k
    const int n = b >> 6;
    const int k = b & 63;
    const int c = threadIdx.x;       // 0..127
    const float* pb = part + (size_t)n * NPT * KC * CC + (size_t)k * CC + c;
    float v = 0.f;
#pragma unroll 4
    for (int pt = 0; pt < NPT; ++pt) v += pb[(size_t)pt * KC * CC];
    const float* psb = ps + (size_t)n * NPT * KC + k;
    float sw = 0.f;
#pragma unroll 4
    for (int pt = 0; pt < NPT; ++pt) sw += psb[(size_t)pt * KC];
    v -= cen[(size_t)k * S1C * CC + c] * sw;

    float ss = v * v;
#pragma unroll
    for (int off = 32; off > 0; off >>= 1) ss += __shfl_down(ss, off);
    if ((c & 63) == 0) w2[c >> 6] = ss;
    __syncthreads();
    const float norm = sqrtf(w2[0] + w2[1]);
    // flat-level norm is exactly sqrt(64)=8 (every row unit-norm, >> EPS)
    const float scale = 1.0f / (fmaxf(norm, EPSF) * 8.0f);
    flat[(size_t)b * CC + c] = v * scale;
}

// ---------------------------------------------------------------------------
// k2 (fallback/atomic mode)
// ---------------------------------------------------------------------------
__global__ __launch_bounds__(128) void k2_final(
    const float* __restrict__ accC, const float* __restrict__ accS,
    const float* __restrict__ cen, float* __restrict__ flat)
{
    __shared__ float w2[2];
    const int b = blockIdx.x;
    const int k = b & 63;
    const int c = threadIdx.x;
    const float v = accC[(size_t)b * CC + c] -
                    cen[(size_t)k * S1C * CC + c] * accS[b];
    float ss = v * v;
#pragma unroll
    for (int off = 32; off > 0; off >>= 1) ss += __shfl_down(ss, off);
    if ((c & 63) == 0) w2[c >> 6] = ss;
    __syncthreads();
    const float norm = sqrtf(w2[0] + w2[1]);
    const float scale = 1.0f / (fmaxf(norm, EPSF) * 8.0f);
    flat[(size_t)b * CC + c] = v * scale;
}

// ---------------------------------------------------------------------------
extern "C" void kernel_launch(void* const* d_in, const int* in_sizes, int n_in,
                              void* d_out, int out_size, void* d_ws, size_t ws_size,
                              hipStream_t stream) {
    const float* x   = (const float*)d_in[0];   // [8][128][44][44]
    const float* cen = (const float*)d_in[1];   // [64][5][128]
    float* out  = (float*)d_out;
    float* flat = out;                           // [8][8192]
    float* sa   = out + (size_t)NB * KC * CC;    // [8][64][1][1936]
    float* ws   = (float*)d_ws;

    unsigned* cenPk = (unsigned*)ws;
    float*    gbias = ws + WS_CENPK;

    if (ws_size >= WS_MAIN_FLOATS * 4) {
        float* part = ws + WS_HDR;
        float* ps   = part + WS_PART;
        k0_pack<<<32, 64, 0, stream>>>(cen, cenPk, gbias);
        k1_main<<<NTILE, 512, 0, stream>>>(x, cenPk, gbias, sa, part, ps, 0);
        k2_slab<<<NB * KC, 128, 0, stream>>>(part, ps, cen, flat);
    } else {
        float* accC = ws + WS_HDR;
        float* accS = accC + (size_t)NB * KC * CC;
        hipMemsetAsync(accC, 0, (size_t)(NB * KC * CC + NB * KC) * 4, stream);
        k0_pack<<<32, 64, 0, stream>>>(cen, cenPk, gbias);
        k1_main<<<NTILE, 512, 0, stream>>>(x, cenPk, gbias, sa, accC, accS, 1);
        k2_final<<<NB * KC, 128, 0, stream>>>(accC, accS, cen, flat);
    }
}

// Round 2
// 90.920 us; speedup vs baseline: 1.1708x; 1.1708x over previous
//
#include <hip/hip_runtime.h>
#include <math.h>

#define NB 8
#define KC 64
#define S1C 5
#define CC 128
#define PP 1936
#define MM 320             /* KC*S1C */
#define PT 64
#define NPT 31             /* ceil(1936/64) */
#define NTILE (NB * NPT)   /* 248 */
#define ALPHAF 1500.0f
#define EPSF 1e-12f

/* ws layout (floats):
   [0, 65536)      cenPk: pre-split bf16 hi/lo cen B-fragments
                   [ks(4)][nt(32)][lane(64)][hi short8, lo short8] = 256 KB
   [65536, 66048)  gbias[512]  (m' = 8k+s padded; s>=5 -> -3e38)
   [66048, ...)    part[248][64][128] ; ps[248][64]                */
#define WS_CENPK 65536
#define WS_GBIAS 512
#define WS_HDR   (WS_CENPK + WS_GBIAS)
#define WS_PART  ((size_t)NTILE * KC * CC)
#define WS_MAIN_FLOATS (WS_HDR + WS_PART + (size_t)NTILE * KC)

typedef __attribute__((ext_vector_type(8))) short short8;
typedef __attribute__((ext_vector_type(4))) float f32x4;

/* pack fp32 -> (bf16_hi << 16) | bf16_lo  (hi = truncate, lo = residual) */
__device__ __forceinline__ unsigned pack_bf16s(float x) {
    unsigned u  = __float_as_uint(x);
    unsigned hi = u & 0xffff0000u;
    float lo    = x - __uint_as_float(hi);
    return hi | (__float_as_uint(lo) >> 16);
}

__device__ __forceinline__ void unpack8(const int4 q0, const int4 q1,
                                        short8& h, short8& l) {
    const int d[8] = {q0.x, q0.y, q0.z, q0.w, q1.x, q1.y, q1.z, q1.w};
#pragma unroll
    for (int j = 0; j < 8; ++j) {
        h[j] = (short)((unsigned)d[j] >> 16);
        l[j] = (short)((unsigned)d[j] & 0xffffu);
    }
}

__device__ __forceinline__ void split8(const float4 a, const float4 b,
                                       short8& h, short8& l) {
    const float f[8] = {a.x, a.y, a.z, a.w, b.x, b.y, b.z, b.w};
#pragma unroll
    for (int j = 0; j < 8; ++j) {
        const unsigned u  = __float_as_uint(f[j]);
        const unsigned hi = u & 0xffff0000u;
        const float lo    = f[j] - __uint_as_float(hi);
        h[j] = (short)(hi >> 16);
        l[j] = (short)(__float_as_uint(lo) >> 16);
    }
}

// ---------------------------------------------------------------------------
// k0: precompute bias[512] and pre-split bf16 hi/lo cen fragments in MFMA
// B-operand lane layout. 32 blocks (one per m'-tile nt) x 64 threads.
// ---------------------------------------------------------------------------
__global__ __launch_bounds__(64) void k0_pack(
    const float* __restrict__ cen, unsigned* __restrict__ cenPk,
    float* __restrict__ gbias)
{
    const int nt   = blockIdx.x;      // 0..31
    const int l    = threadIdx.x;     // 0..63
    const int l15  = l & 15;
    const int quad = l >> 4;
    const int mp   = nt * 16 + l15;   // padded m' = 8k+s
    const int s    = mp & 7;
    const bool valid = (s < 5);
    const int wrow = 5 * (mp >> 3) + s;
    short8* dst8 = (short8*)cenPk;
    float ss = 0.f;
#pragma unroll
    for (int ks = 0; ks < 4; ++ks) {
        float4 v0 = make_float4(0.f, 0.f, 0.f, 0.f), v1 = v0;
        if (valid) {
            const float* wp = cen + (size_t)wrow * CC + ks * 32 + quad * 8;
            v0 = *(const float4*)wp;
            v1 = *(const float4*)(wp + 4);
        }
        ss += v0.x * v0.x + v0.y * v0.y + v0.z * v0.z + v0.w * v0.w
            + v1.x * v1.x + v1.y * v1.y + v1.z * v1.z + v1.w * v1.w;
        short8 h, lo;
        split8(v0, v1, h, lo);
        const int base = ((ks * 32 + nt) * 64 + l) * 2;
        dst8[base]     = h;
        dst8[base + 1] = lo;
    }
    ss += __shfl_xor(ss, 16);
    ss += __shfl_xor(ss, 32);
    if (quad == 0) gbias[mp] = valid ? (-ALPHAF * sqrtf(ss)) : -3.0e38f;
}

// ---------------------------------------------------------------------------
// k1: per (n, p-tile of 64), 1024 threads = 16 waves, 3 barriers.
// Logits via MFMA: D[p][m'] = x^T cen, m' = 8k+s padded (s>=5 masked).
// Wave handles m'-tiles nt = {2wid, 2wid+1} -> k = 4wid..4wid+3.
// B-frags direct from cenPk (k0 pre-packed, L2-resident; no split VALU).
// beta: 8-lane shfl butterflies. alpha: per-wave partials + per-lane finalize.
// stage-C via bf16-split MFMA.
// ---------------------------------------------------------------------------
__global__ __launch_bounds__(1024, 4) void k1_main(
    const float* __restrict__ x, const unsigned* __restrict__ cenPk,
    const float* __restrict__ gbias,
    float* __restrict__ sa_out, float* __restrict__ outC,
    float* __restrict__ outS, int mode)
{
    __shared__ unsigned xbuf[CC * 68];   // 34816 B; phase1: [p][132] packed x^T; phase3: [c][68] packed x
    __shared__ unsigned war[KC * 68];    // 17408 B packed wa [k][p]
    __shared__ float2   ap[16 * 66];     //  8448 B alpha partials [wid][p]
    __shared__ float    bias_p[512];     //  2048 B padded bias, m' = 8k+s

    const int tid  = threadIdx.x;
    const int lane = tid & 63;
    const int wid  = tid >> 6;           // 0..15
    const int quad = lane >> 4;
    const int l15  = lane & 15;
    const int bx   = blockIdx.x;
    const int n    = bx / NPT;
    const int pt   = bx - n * NPT;
    const int p0   = pt * PT;

    // ---- phase 0: stage x -> xbuf[p][132] packed bf16 hi|lo; bias load ----
    const float* xn = x + (size_t)n * CC * PP;
    for (int idx = tid; idx < CC * 16; idx += 1024) {
        const int c = idx >> 4;
        const int q = idx & 15;
        const int p = 4 * q;
        float4 v = make_float4(0.f, 0.f, 0.f, 0.f);
        if (p0 + p < PP) v = *(const float4*)(xn + (size_t)c * PP + p0 + p);
        xbuf[(p + 0) * 132 + c] = pack_bf16s(v.x);
        xbuf[(p + 1) * 132 + c] = pack_bf16s(v.y);
        xbuf[(p + 2) * 132 + c] = pack_bf16s(v.z);
        xbuf[(p + 3) * 132 + c] = pack_bf16s(v.w);
    }
    if (tid < 512) bias_p[tid] = gbias[tid];
    __syncthreads();

    // ---- phase 1: logits MFMA ----
    f32x4 dacc[4][2];
#pragma unroll
    for (int a = 0; a < 4; ++a) {
        dacc[a][0] = (f32x4){0.f, 0.f, 0.f, 0.f};
        dacc[a][1] = (f32x4){0.f, 0.f, 0.f, 0.f};
    }
    const short8* cpk8 = (const short8*)cenPk;

#pragma unroll 1
    for (int ks = 0; ks < 4; ++ks) {
        short8 bh[2], bl[2];
#pragma unroll
        for (int i = 0; i < 2; ++i) {
            const int boff = ((ks * 32 + 2 * wid + i) * 64 + lane) * 2;
            bh[i] = cpk8[boff];
            bl[i] = cpk8[boff + 1];
        }
#pragma unroll
        for (int a = 0; a < 4; ++a) {
            const int abase = (a * 16 + l15) * 132 + ks * 32 + quad * 8;
            const int4 q0 = *(const int4*)(&xbuf[abase]);
            const int4 q1 = *(const int4*)(&xbuf[abase + 4]);
            short8 ah, al;
            unpack8(q0, q1, ah, al);
#pragma unroll
            for (int i = 0; i < 2; ++i) {
                dacc[a][i] = __builtin_amdgcn_mfma_f32_16x16x32_bf16(ah, bh[i], dacc[a][i], 0, 0, 0);
                dacc[a][i] = __builtin_amdgcn_mfma_f32_16x16x32_bf16(ah, bl[i], dacc[a][i], 0, 0, 0);
                dacc[a][i] = __builtin_amdgcn_mfma_f32_16x16x32_bf16(al, bh[i], dacc[a][i], 0, 0, 0);
            }
        }
    }

    // lg in place: lg = 2*ALPHA*dot + bias (invalid cols -> -3e38)
    const float bv0 = bias_p[(2 * wid + 0) * 16 + l15];
    const float bv1 = bias_p[(2 * wid + 1) * 16 + l15];
#pragma unroll
    for (int a = 0; a < 4; ++a)
#pragma unroll
        for (int r = 0; r < 4; ++r) {
            dacc[a][0][r] = 2.f * ALPHAF * dacc[a][0][r] + bv0;
            dacc[a][1][r] = 2.f * ALPHAF * dacc[a][1][r] + bv1;
        }

    // alpha partials over this wave's 4 k (i-regs x shfl_xor 8), s0 lanes hold lg0
#pragma unroll
    for (int a = 0; a < 4; ++a) {
        f32x4 mx4, se4;
#pragma unroll
        for (int r = 0; r < 4; ++r) {
            float m_ = fmaxf(dacc[a][0][r], dacc[a][1][r]);
            m_ = fmaxf(m_, __shfl_xor(m_, 8));
            float se = __expf(dacc[a][0][r] - m_) + __expf(dacc[a][1][r] - m_);
            se += __shfl_xor(se, 8);
            mx4[r] = m_; se4[r] = se;
        }
        if (l15 == 0) {
#pragma unroll
            for (int r = 0; r < 4; ++r)
                ap[wid * 66 + a * 16 + 4 * quad + r] = make_float2(mx4[r], se4[r]);
        }
    }
    __syncthreads();

    // ---- phase 2: alpha finalize (lane = p), beta+sa, war, xc restage ----
    float gmv, arv;
    {
        float gm = -3.0e38f;
#pragma unroll
        for (int w = 0; w < 16; ++w) gm = fmaxf(gm, ap[w * 66 + lane].x);
        float s = 0.f;
#pragma unroll
        for (int w = 0; w < 16; ++w) {
            const float2 v = ap[w * 66 + lane];
            s += v.y * __expf(v.x - gm);
        }
        gmv = gm; arv = 1.0f / s;
    }

    float* san = sa_out + (size_t)n * KC * PP;
    float psum[2] = {0.f, 0.f};
    const bool is_s0 = ((l15 & 7) == 0);
#pragma unroll
    for (int a = 0; a < 4; ++a) {
#pragma unroll
        for (int i = 0; i < 2; ++i) {
            const f32x4 lg = dacc[a][i];
            f32x4 sav; unsigned wpk[4];
#pragma unroll
            for (int r = 0; r < 4; ++r) {
                float m_ = lg[r];
                m_ = fmaxf(m_, __shfl_xor(m_, 1));
                m_ = fmaxf(m_, __shfl_xor(m_, 2));
                m_ = fmaxf(m_, __shfl_xor(m_, 4));
                const float e_ = __expf(lg[r] - m_);
                float d_ = e_;
                d_ += __shfl_xor(d_, 1);
                d_ += __shfl_xor(d_, 2);
                d_ += __shfl_xor(d_, 4);
                const int p = a * 16 + 4 * quad + r;
                const float gm_p = __shfl(gmv, p);
                const float ar_p = __shfl(arv, p);
                const float sa = __expf(lg[r] - gm_p) * ar_p * (e_ / d_);
                const bool pvalid = (p0 + p) < PP;
                const float wa = pvalid ? (1.0f + sa) : 0.0f;
                sav[r] = sa;
                wpk[r] = pack_bf16s(wa);
                psum[i] += wa;
            }
            const int k = 4 * wid + 2 * i + (l15 >> 3);
            if (is_s0) {
                *(int4*)(&war[k * 68 + a * 16 + 4 * quad]) = *(const int4*)wpk;
                const int pg = p0 + a * 16 + 4 * quad;
                if (pg < PP) *(float4*)(&san[(size_t)k * PP + pg]) = *(const float4*)&sav;
            }
        }
    }
#pragma unroll
    for (int i = 0; i < 2; ++i) {
        float s = psum[i];
        s += __shfl_xor(s, 16);
        s += __shfl_xor(s, 32);
        if (is_s0 && quad == 0) {
            const int k = 4 * wid + 2 * i + (l15 >> 3);
            if (mode == 0) outS[(size_t)bx * KC + k] = s;
            else           atomicAdd(&outS[(size_t)n * KC + k], s);
        }
    }
    // restage x -> xbuf[c][68] packed (phase-1 reads finished before barrier)
    {
        const int c  = tid >> 3;
        const int po = (tid & 7) * 8;
        float4 v0 = make_float4(0.f, 0.f, 0.f, 0.f), v1 = v0;
        if (p0 + po < PP) {
            const float* src = xn + (size_t)c * PP + p0 + po;
            v0 = *(const float4*)src;
            v1 = *(const float4*)(src + 4);
        }
        unsigned pk[8];
        pk[0] = pack_bf16s(v0.x); pk[1] = pack_bf16s(v0.y);
        pk[2] = pack_bf16s(v0.z); pk[3] = pack_bf16s(v0.w);
        pk[4] = pack_bf16s(v1.x); pk[5] = pack_bf16s(v1.y);
        pk[6] = pack_bf16s(v1.z); pk[7] = pack_bf16s(v1.w);
        *(int4*)(&xbuf[c * 68 + po])     = *(const int4*)&pk[0];
        *(int4*)(&xbuf[c * 68 + po + 4]) = *(const int4*)&pk[4];
    }
    __syncthreads();

    // ---- phase 3: stage-C MFMA: C[k][c] = sum_p wa*x ----
    const int kt  = wid & 3;
    const int ct0 = (wid >> 2) * 2;
    f32x4 cacc[2];
    cacc[0] = (f32x4){0.f, 0.f, 0.f, 0.f};
    cacc[1] = (f32x4){0.f, 0.f, 0.f, 0.f};
#pragma unroll
    for (int ks = 0; ks < 64; ks += 32) {
        const int abase = (kt * 16 + l15) * 68 + ks + quad * 8;
        const int4 qa0 = *(const int4*)(&war[abase]);
        const int4 qa1 = *(const int4*)(&war[abase + 4]);
        short8 ah, al;
        unpack8(qa0, qa1, ah, al);
#pragma unroll
        for (int t = 0; t < 2; ++t) {
            const int c = (ct0 + t) * 16 + l15;
            const int bbase = c * 68 + ks + quad * 8;
            const int4 qb0 = *(const int4*)(&xbuf[bbase]);
            const int4 qb1 = *(const int4*)(&xbuf[bbase + 4]);
            short8 bh, bl;
            unpack8(qb0, qb1, bh, bl);
            cacc[t] = __builtin_amdgcn_mfma_f32_16x16x32_bf16(ah, bh, cacc[t], 0, 0, 0);
            cacc[t] = __builtin_amdgcn_mfma_f32_16x16x32_bf16(ah, bl, cacc[t], 0, 0, 0);
            cacc[t] = __builtin_amdgcn_mfma_f32_16x16x32_bf16(al, bh, cacc[t], 0, 0, 0);
        }
    }
    if (mode == 0) {
        float* dst = outC + (size_t)bx * KC * CC;
#pragma unroll
        for (int t = 0; t < 2; ++t) {
            const int c = (ct0 + t) * 16 + l15;
#pragma unroll
            for (int r = 0; r < 4; ++r)
                dst[(kt * 16 + 4 * quad + r) * CC + c] = cacc[t][r];
        }
    } else {
        float* dst = outC + (size_t)n * KC * CC;
#pragma unroll
        for (int t = 0; t < 2; ++t) {
            const int c = (ct0 + t) * 16 + l15;
#pragma unroll
            for (int r = 0; r < 4; ++r)
                atomicAdd(&dst[(kt * 16 + 4 * quad + r) * CC + c], cacc[t][r]);
        }
    }
}

// ---------------------------------------------------------------------------
// k2 (slab mode): reduce 31 partial slabs, subtract rep*Swa, normalize, /8
// ---------------------------------------------------------------------------
__global__ __launch_bounds__(128) void k2_slab(
    const float* __restrict__ part, const float* __restrict__ ps,
    const float* __restrict__ cen, float* __restrict__ flat)
{
    __shared__ float w2[2];
    const int b = blockIdx.x;        // n*64 + k
    const int n = b >> 6;
    const int k = b & 63;
    const int c = threadIdx.x;       // 0..127
    const float* pb = part + (size_t)n * NPT * KC * CC + (size_t)k * CC + c;
    float v = 0.f;
#pragma unroll 8
    for (int pt = 0; pt < NPT; ++pt) v += pb[(size_t)pt * KC * CC];
    const float* psb = ps + (size_t)n * NPT * KC + k;
    float sw = 0.f;
#pragma unroll
    for (int pt = 0; pt < NPT; ++pt) sw += psb[(size_t)pt * KC];
    v -= cen[(size_t)k * S1C * CC + c] * sw;

    float ss = v * v;
#pragma unroll
    for (int off = 32; off > 0; off >>= 1) ss += __shfl_down(ss, off);
    if ((c & 63) == 0) w2[c >> 6] = ss;
    __syncthreads();
    const float norm = sqrtf(w2[0] + w2[1]);
    // flat-level norm is exactly sqrt(64)=8 (every row unit-norm, >> EPS)
    const float scale = 1.0f / (fmaxf(norm, EPSF) * 8.0f);
    flat[(size_t)b * CC + c] = v * scale;
}

// ---------------------------------------------------------------------------
// k2 (fallback/atomic mode)
// ---------------------------------------------------------------------------
__global__ __launch_bounds__(128) void k2_final(
    const float* __restrict__ accC, const float* __restrict__ accS,
    const float* __restrict__ cen, float* __restrict__ flat)
{
    __shared__ float w2[2];
    const int b = blockIdx.x;
    const int k = b & 63;
    const int c = threadIdx.x;
    const float v = accC[(size_t)b * CC + c] -
                    cen[(size_t)k * S1C * CC + c] * accS[b];
    float ss = v * v;
#pragma unroll
    for (int off = 32; off > 0; off >>= 1) ss += __shfl_down(ss, off);
    if ((c & 63) == 0) w2[c >> 6] = ss;
    __syncthreads();
    const float norm = sqrtf(w2[0] + w2[1]);
    const float scale = 1.0f / (fmaxf(norm, EPSF) * 8.0f);
    flat[(size_t)b * CC + c] = v * scale;
}

// ---------------------------------------------------------------------------
extern "C" void kernel_launch(void* const* d_in, const int* in_sizes, int n_in,
                              void* d_out, int out_size, void* d_ws, size_t ws_size,
                              hipStream_t stream) {
    const float* x   = (const float*)d_in[0];   // [8][128][44][44]
    const float* cen = (const float*)d_in[1];   // [64][5][128]
    float* out  = (float*)d_out;
    float* flat = out;                           // [8][8192]
    float* sa   = out + (size_t)NB * KC * CC;    // [8][64][1][1936]
    float* ws   = (float*)d_ws;

    unsigned* cenPk = (unsigned*)ws;
    float*    gbias = ws + WS_CENPK;

    if (ws_size >= WS_MAIN_FLOATS * 4) {
        float* part = ws + WS_HDR;
        float* ps   = part + WS_PART;
        k0_pack<<<32, 64, 0, stream>>>(cen, cenPk, gbias);
        k1_main<<<NTILE, 1024, 0, stream>>>(x, cenPk, gbias, sa, part, ps, 0);
        k2_slab<<<NB * KC, 128, 0, stream>>>(part, ps, cen, flat);
    } else {
        float* accC = ws + WS_HDR;
        float* accS = accC + (size_t)NB * KC * CC;
        hipMemsetAsync(accC, 0, (size_t)(NB * KC * CC + NB * KC) * 4, stream);
        k0_pack<<<32, 64, 0, stream>>>(cen, cenPk, gbias);
        k1_main<<<NTILE, 1024, 0, stream>>>(x, cenPk, gbias, sa, accC, accS, 1);
        k2_final<<<NB * KC, 128, 0, stream>>>(accC, accS, cen, flat);
    }
}